// Round 15
// baseline (2269.918 us; speedup 1.0000x reference)
//
#include <hip/hip_runtime.h>
#include <math.h>

#define SEQ   2048
#define BATCH 64
#define IN    256
#define HID   256
#define NBLK  (SEQ / 8)

typedef _Float16 hf2 __attribute__((ext_vector_type(2)));
typedef _Float16 hf4 __attribute__((ext_vector_type(4)));
typedef _Float16 hf8 __attribute__((ext_vector_type(8)));
typedef float    f32x2 __attribute__((ext_vector_type(2)));
typedef float    f32x4 __attribute__((ext_vector_type(4)));

static __device__ __forceinline__ float dot2(hf2 a, hf2 b, float c) {
#if __has_builtin(__builtin_amdgcn_fdot2)
    return __builtin_amdgcn_fdot2(a, b, c, false);
#else
    return fmaf((float)a.x, (float)b.x, fmaf((float)a.y, (float)b.y, c));
#endif
}

static __device__ __forceinline__ float fast_sigmoid(float x) {
    return __builtin_amdgcn_rcpf(1.0f + __expf(-x));
}

static __device__ __forceinline__ float fast_tanh(float x) {
    const float e = __expf(-2.0f * x);
    return fmaf(2.0f, __builtin_amdgcn_rcpf(1.0f + e), -1.0f);
}

static __device__ __forceinline__ hf8 cvt8(const float4& a, const float4& b) {
    hf8 f;
    f[0] = (_Float16)a.x; f[1] = (_Float16)a.y;
    f[2] = (_Float16)a.z; f[3] = (_Float16)a.w;
    f[4] = (_Float16)b.x; f[5] = (_Float16)b.y;
    f[6] = (_Float16)b.z; f[7] = (_Float16)b.w;
    return f;
}

// LDS-ordering barrier: no vmcnt(0) drain (R13 win), no sched_barrier pin.
static __device__ __forceinline__ void bar_lds() {
    asm volatile("s_waitcnt lgkmcnt(0)" ::: "memory");
    __builtin_amdgcn_s_barrier();
}

// ---------------------------------------------------------------------------
// Kernel 0: Wz,Wh fp32 -> W16 [512][256] fp16
// ---------------------------------------------------------------------------
__global__ __launch_bounds__(256) void w16_kernel(
    const float* __restrict__ Wz, const float* __restrict__ Wh,
    _Float16* __restrict__ W16)
{
    const int idx = blockIdx.x * 256 + threadIdx.x;
    const int row = idx >> 8;
    const int col = idx & 255;
    const float v = (row < 256) ? Wz[row * 256 + col] : Wh[(row - 256) * 256 + col];
    W16[idx] = (_Float16)v;
}

// ---------------------------------------------------------------------------
// Kernel A: input projections via mfma_f32_16x16x32_f16 (validated R4+).
// ---------------------------------------------------------------------------
__global__ __launch_bounds__(256) void proj_mfma_kernel(
    const float* __restrict__ x,
    const _Float16* __restrict__ W16,
    const float* __restrict__ bz, const float* __restrict__ cz,
    const float* __restrict__ bh, const float* __restrict__ ch,
    _Float16* __restrict__ xz16,
    float* __restrict__ xh_out)
{
    const int tid  = threadIdx.x;
    const int lane = tid & 63;
    const int w    = tid >> 6;
    const int m0   = blockIdx.x * 16;
    const int col0 = w * 128;

    const int r = lane & 15;
    const int g = lane >> 4;

    f32x4 acc[8] = {f32x4{0,0,0,0}, f32x4{0,0,0,0}, f32x4{0,0,0,0}, f32x4{0,0,0,0},
                    f32x4{0,0,0,0}, f32x4{0,0,0,0}, f32x4{0,0,0,0}, f32x4{0,0,0,0}};

    const float*    xrow  = x   + (size_t)(m0 + r) * IN + g * 8;
    const _Float16* wbase = W16 + (size_t)(col0 + r) * IN + g * 8;

#pragma unroll
    for (int kt = 0; kt < 8; ++kt) {
        const float4 xa = *reinterpret_cast<const float4*>(xrow + kt * 32);
        const float4 xb = *reinterpret_cast<const float4*>(xrow + kt * 32 + 4);
        const hf8 a = cvt8(xa, xb);
#pragma unroll
        for (int t = 0; t < 8; ++t) {
            const hf8 bfrag = *reinterpret_cast<const hf8*>(
                wbase + (size_t)t * 16 * IN + kt * 32);
            acc[t] = __builtin_amdgcn_mfma_f32_16x16x32_f16(a, bfrag, acc[t], 0, 0, 0);
        }
    }

    if (w < 2) {
#pragma unroll
        for (int t = 0; t < 8; ++t) {
            const int c = col0 + t * 16 + r;
            const float bsum = bz[c] + cz[c];
#pragma unroll
            for (int reg = 0; reg < 4; ++reg) {
                const int m = m0 + 4 * g + reg;
                xz16[(size_t)m * HID + c] = (_Float16)(acc[t][reg] + bsum);
            }
        }
    } else {
#pragma unroll
        for (int t = 0; t < 8; ++t) {
            const int c = col0 - 256 + t * 16 + r;
            const float bsum = bh[c] + ch[c];
#pragma unroll
            for (int reg = 0; reg < 4; ++reg) {
                const int m = m0 + 4 * g + reg;
                xh_out[(size_t)m * HID + c] = acc[t][reg] + bsum;
            }
        }
    }
}

// ---------------------------------------------------------------------------
// Kernel B: dot2 (VALU) recurrence — zero wasted FLOPs (the R15 insight:
// broadcast-MFMA pays 1240 cy/CU/step of matrix pipe for 1/16 useful work;
// v_dot2_f32_f16 does the same matvec in 512 cy/SIMD of VALU issue).
// One WG per batch (64 WGs), 1024 threads = 16 waves (4/SIMD).
//   - Thread (og = tid>>2, q = tid&3): owns Uz[og][64q..64q+64) and
//     Uh[og][...] as 64 packed-hf2 VGPRs; accumulates z/h~ partials in fp32
//     (4 independent dot2 chains for ILP).
//   - h operand: fp16 in LDS [2][256] linear; per-chunk reads have 4
//     distinct addrs/wave (q) -> broadcast, conflict-free.
//   - Reduce over q: 2x shfl_xor (DPP) per acc — results born lane-local,
//     no sbuf exchange (shorter serial chain than the MFMA variants).
//   - Epilogue: all 4 q-lanes compute redundantly (no divergence), q==0
//     stores (4B out, 2B hbuf).
//   - R13/R14 infrastructure: LDS x-block staging (8 steps, dbuf, 2-block
//     prefetch), lgkm-only barrier, fire-and-forget h stores.
// ---------------------------------------------------------------------------
__global__ __launch_bounds__(1024, 1) void rec_dot2_kernel(
    const float* __restrict__ hidden0,
    const float* __restrict__ Uz,
    const float* __restrict__ Uh,
    const _Float16* __restrict__ xz16,
    float* __restrict__ out,
    float* __restrict__ h_final)
{
    const int b   = blockIdx.x;         // batch element (one per WG)
    const int tid = threadIdx.x;
    const int og  = tid >> 2;           // output 0..255
    const int q   = tid & 3;            // k-slice 0..3

    __shared__ __align__(16) _Float16 hbuf[2][256];        // h operand, dbuf
    __shared__ __align__(16) _Float16 xzs[2][8][256];      // xz block stage
    __shared__ __align__(16) float    xhs[2][8][256];      // xh block stage

    // ---- U slices -> registers (64 VGPRs) ----
    hf2 uz[32], uh[32];
    {
        const float* pz = Uz + (size_t)og * HID + q * 64;
        const float* ph = Uh + (size_t)og * HID + q * 64;
#pragma unroll
        for (int i = 0; i < 16; ++i) {
            float4 v;
            v = *reinterpret_cast<const float4*>(pz + 4 * i);
            uz[2*i]   = hf2{(_Float16)v.x, (_Float16)v.y};
            uz[2*i+1] = hf2{(_Float16)v.z, (_Float16)v.w};
            v = *reinterpret_cast<const float4*>(ph + 4 * i);
            uh[2*i]   = hf2{(_Float16)v.x, (_Float16)v.y};
            uh[2*i+1] = hf2{(_Float16)v.z, (_Float16)v.w};
        }
    }

    // ---- init LDS h + fp32 h state (replicated across q) ----
    if (tid < 256) {
        hbuf[0][tid] = (_Float16)hidden0[b * HID + tid];
    }
    float hp = hidden0[b * HID + og];
    float* pst = out + (size_t)b * HID + og;

    // ---- x-staging: thread (srow, 2-elem chunk) ----
    const int srow = tid >> 7;           // 0..7 (step within block)
    const int scol = (tid & 127) * 2;    // 2-elem chunk
    hf2   rz;
    f32x2 rh;
    {
        const size_t a0 = ((size_t)srow * BATCH + b) * HID + scol;
        *reinterpret_cast<hf2*>(&xzs[0][srow][scol]) =
            *reinterpret_cast<const hf2*>(xz16 + a0);
        *reinterpret_cast<f32x2*>(&xhs[0][srow][scol]) =
            *reinterpret_cast<const f32x2*>(out + a0);
        const size_t a1 = ((size_t)(8 + srow) * BATCH + b) * HID + scol;
        rz = *reinterpret_cast<const hf2*>(xz16 + a1);
        rh = *reinterpret_cast<const f32x2*>(out + a1);
    }
    __syncthreads();

    for (int j = 0; j < NBLK; ++j) {
        const int jb = j & 1;
#pragma unroll
        for (int s = 0; s < 8; ++s) {
            // staged x reads (broadcast per og-group)
            const float xzc = (float)xzs[jb][s][og];
            const float xhc = xhs[jb][s][og];
            // matvec slice: 64 dot2, 4 independent chains
            const _Float16* hsl = &hbuf[s & 1][q * 64];
            float za = 0.f, zb = 0.f, ha = 0.f, hb = 0.f;
#pragma unroll
            for (int c8 = 0; c8 < 8; ++c8) {
                const hf8 hv = *reinterpret_cast<const hf8*>(hsl + 8 * c8);
                const hf2 p0 = __builtin_shufflevector(hv, hv, 0, 1);
                const hf2 p1 = __builtin_shufflevector(hv, hv, 2, 3);
                const hf2 p2 = __builtin_shufflevector(hv, hv, 4, 5);
                const hf2 p3 = __builtin_shufflevector(hv, hv, 6, 7);
                if (c8 & 1) {
                    zb = dot2(p0, uz[4*c8+0], zb);
                    zb = dot2(p1, uz[4*c8+1], zb);
                    zb = dot2(p2, uz[4*c8+2], zb);
                    zb = dot2(p3, uz[4*c8+3], zb);
                    hb = dot2(p0, uh[4*c8+0], hb);
                    hb = dot2(p1, uh[4*c8+1], hb);
                    hb = dot2(p2, uh[4*c8+2], hb);
                    hb = dot2(p3, uh[4*c8+3], hb);
                } else {
                    za = dot2(p0, uz[4*c8+0], za);
                    za = dot2(p1, uz[4*c8+1], za);
                    za = dot2(p2, uz[4*c8+2], za);
                    za = dot2(p3, uz[4*c8+3], za);
                    ha = dot2(p0, uh[4*c8+0], ha);
                    ha = dot2(p1, uh[4*c8+1], ha);
                    ha = dot2(p2, uh[4*c8+2], ha);
                    ha = dot2(p3, uh[4*c8+3], ha);
                }
            }
            float accz = za + zb;
            float acch = ha + hb;
            // reduce over the 4 q-lanes (DPP butterfly)
            accz += __shfl_xor(accz, 1);
            accz += __shfl_xor(accz, 2);
            acch += __shfl_xor(acch, 1);
            acch += __shfl_xor(acch, 2);
            // epilogue: all q-lanes compute (replicated), q==0 stores
            const float z  = fast_sigmoid(accz + xzc);
            const float th = fast_tanh(acch + xhc);
            hp = fmaf(z, th - hp, hp);
            if (q == 0) {
                *pst = hp;                       // fire-and-forget HBM store
                hbuf[(s + 1) & 1][og] = (_Float16)hp;
            }
            pst += (size_t)BATCH * HID;
            // block boundary: relay regs -> LDS, issue loads 2 blocks ahead
            if (s == 7 && j + 1 < NBLK) {
                *reinterpret_cast<hf2*>(&xzs[jb ^ 1][srow][scol])   = rz;
                *reinterpret_cast<f32x2*>(&xhs[jb ^ 1][srow][scol]) = rh;
                int trow = 8 * (j + 2) + srow;
                if (trow >= SEQ) trow = SEQ - 1;     // tail clamp (unused)
                const size_t an = ((size_t)trow * BATCH + b) * HID + scol;
                rz = *reinterpret_cast<const hf2*>(xz16 + an);
                rh = *reinterpret_cast<const f32x2*>(out + an);
            }
            bar_lds();
        }
    }

    if (q == 0) {
        h_final[(size_t)b * HID + og] = hp;
    }
}

extern "C" void kernel_launch(void* const* d_in, const int* in_sizes, int n_in,
                              void* d_out, int out_size, void* d_ws, size_t ws_size,
                              hipStream_t stream) {
    const float* x      = (const float*)d_in[0];
    const float* hidden = (const float*)d_in[1];
    const float* Wz     = (const float*)d_in[2];
    const float* bz     = (const float*)d_in[3];
    const float* Uz     = (const float*)d_in[4];
    const float* cz     = (const float*)d_in[5];
    const float* Wh     = (const float*)d_in[6];
    const float* bh     = (const float*)d_in[7];
    const float* Uh     = (const float*)d_in[8];
    const float* ch     = (const float*)d_in[9];

    float* out     = (float*)d_out;                        // [SEQ*BATCH*HID]
    float* h_final = out + (size_t)SEQ * BATCH * HID;      // [BATCH*HID]

    _Float16* xz16 = (_Float16*)d_ws;                               // 64 MiB
    _Float16* W16  = (_Float16*)((char*)d_ws + ((size_t)64 << 20)); // 256 KiB

    w16_kernel<<<512, 256, 0, stream>>>(Wz, Wh, W16);

    proj_mfma_kernel<<<(SEQ * BATCH) / 16, 256, 0, stream>>>(
        x, W16, bz, cz, bh, ch, xz16, out);

    rec_dot2_kernel<<<BATCH, 1024, 0, stream>>>(
        hidden, Uz, Uh, xz16, out, h_final);
}

// Round 16
// 2219.134 us; speedup vs baseline: 1.0229x; 1.0229x over previous
//
#include <hip/hip_runtime.h>
#include <math.h>

#define SEQ   2048
#define BATCH 64
#define IN    256
#define HID   256
#define NBLK  (SEQ / 8)

typedef _Float16 hf2 __attribute__((ext_vector_type(2)));
typedef _Float16 hf4 __attribute__((ext_vector_type(4)));
typedef _Float16 hf8 __attribute__((ext_vector_type(8)));
typedef float    f32x2 __attribute__((ext_vector_type(2)));
typedef float    f32x4 __attribute__((ext_vector_type(4)));

static __device__ __forceinline__ float dot2(hf2 a, hf2 b, float c) {
#if __has_builtin(__builtin_amdgcn_fdot2)
    return __builtin_amdgcn_fdot2(a, b, c, false);
#else
    return fmaf((float)a.x, (float)b.x, fmaf((float)a.y, (float)b.y, c));
#endif
}

static __device__ __forceinline__ float fast_sigmoid(float x) {
    return __builtin_amdgcn_rcpf(1.0f + __expf(-x));
}

static __device__ __forceinline__ float fast_tanh(float x) {
    const float e = __expf(-2.0f * x);
    return fmaf(2.0f, __builtin_amdgcn_rcpf(1.0f + e), -1.0f);
}

static __device__ __forceinline__ hf8 cvt8(const float4& a, const float4& b) {
    hf8 f;
    f[0] = (_Float16)a.x; f[1] = (_Float16)a.y;
    f[2] = (_Float16)a.z; f[3] = (_Float16)a.w;
    f[4] = (_Float16)b.x; f[5] = (_Float16)b.y;
    f[6] = (_Float16)b.z; f[7] = (_Float16)b.w;
    return f;
}

// LDS-ordering barrier: no vmcnt(0) drain (R13 win), no sched_barrier pin.
static __device__ __forceinline__ void bar_lds() {
    asm volatile("s_waitcnt lgkmcnt(0)" ::: "memory");
    __builtin_amdgcn_s_barrier();
}

// ---------------------------------------------------------------------------
// Kernel 0: Wz,Wh fp32 -> W16 [512][256] fp16
// ---------------------------------------------------------------------------
__global__ __launch_bounds__(256) void w16_kernel(
    const float* __restrict__ Wz, const float* __restrict__ Wh,
    _Float16* __restrict__ W16)
{
    const int idx = blockIdx.x * 256 + threadIdx.x;
    const int row = idx >> 8;
    const int col = idx & 255;
    const float v = (row < 256) ? Wz[row * 256 + col] : Wh[(row - 256) * 256 + col];
    W16[idx] = (_Float16)v;
}

// ---------------------------------------------------------------------------
// Kernel A: input projections via mfma_f32_16x16x32_f16 (validated R4+).
// ---------------------------------------------------------------------------
__global__ __launch_bounds__(256) void proj_mfma_kernel(
    const float* __restrict__ x,
    const _Float16* __restrict__ W16,
    const float* __restrict__ bz, const float* __restrict__ cz,
    const float* __restrict__ bh, const float* __restrict__ ch,
    _Float16* __restrict__ xz16,
    float* __restrict__ xh_out)
{
    const int tid  = threadIdx.x;
    const int lane = tid & 63;
    const int w    = tid >> 6;
    const int m0   = blockIdx.x * 16;
    const int col0 = w * 128;

    const int r = lane & 15;
    const int g = lane >> 4;

    f32x4 acc[8] = {f32x4{0,0,0,0}, f32x4{0,0,0,0}, f32x4{0,0,0,0}, f32x4{0,0,0,0},
                    f32x4{0,0,0,0}, f32x4{0,0,0,0}, f32x4{0,0,0,0}, f32x4{0,0,0,0}};

    const float*    xrow  = x   + (size_t)(m0 + r) * IN + g * 8;
    const _Float16* wbase = W16 + (size_t)(col0 + r) * IN + g * 8;

#pragma unroll
    for (int kt = 0; kt < 8; ++kt) {
        const float4 xa = *reinterpret_cast<const float4*>(xrow + kt * 32);
        const float4 xb = *reinterpret_cast<const float4*>(xrow + kt * 32 + 4);
        const hf8 a = cvt8(xa, xb);
#pragma unroll
        for (int t = 0; t < 8; ++t) {
            const hf8 bfrag = *reinterpret_cast<const hf8*>(
                wbase + (size_t)t * 16 * IN + kt * 32);
            acc[t] = __builtin_amdgcn_mfma_f32_16x16x32_f16(a, bfrag, acc[t], 0, 0, 0);
        }
    }

    if (w < 2) {
#pragma unroll
        for (int t = 0; t < 8; ++t) {
            const int c = col0 + t * 16 + r;
            const float bsum = bz[c] + cz[c];
#pragma unroll
            for (int reg = 0; reg < 4; ++reg) {
                const int m = m0 + 4 * g + reg;
                xz16[(size_t)m * HID + c] = (_Float16)(acc[t][reg] + bsum);
            }
        }
    } else {
#pragma unroll
        for (int t = 0; t < 8; ++t) {
            const int c = col0 - 256 + t * 16 + r;
            const float bsum = bh[c] + ch[c];
#pragma unroll
            for (int reg = 0; reg < 4; ++reg) {
                const int m = m0 + 4 * g + reg;
                xh_out[(size_t)m * HID + c] = acc[t][reg] + bsum;
            }
        }
    }
}

// ---------------------------------------------------------------------------
// Kernel B: dot2 (VALU) recurrence, R15 structure + the R3-proven SKEWED h
// layout (the R16 fix): addr(k) = k + (k>>5)*8 halves.
//   - slice base q*80 halves = q*160 B -> first-dword banks {0,8,16,24};
//     each b128's dwords hit disjoint banks -> conflict-free (R3: 0 measured;
//     R15's linear layout was a 4-way conflict on EVERY h read, 6.7e7 total).
//   - reads: offset 8*c8 + (c8>>2)*8 within slice (skips the skew gap);
//     writes/init use og + (og>>5)*8. All 16B-aligned.
// Everything else unchanged from R15: one WG/batch, 1024 thr (4 waves/SIMD),
// 64 dot2/thread (zero wasted FLOPs), DPP butterfly reduce, all-lane fast
// epilogue with q==0 stores, LDS x-block staging, lgkm-only barrier.
// ---------------------------------------------------------------------------
__global__ __launch_bounds__(1024, 1) void rec_dot2_kernel(
    const float* __restrict__ hidden0,
    const float* __restrict__ Uz,
    const float* __restrict__ Uh,
    const _Float16* __restrict__ xz16,
    float* __restrict__ out,
    float* __restrict__ h_final)
{
    const int b   = blockIdx.x;         // batch element (one per WG)
    const int tid = threadIdx.x;
    const int og  = tid >> 2;           // output 0..255
    const int q   = tid & 3;            // k-slice 0..3

    __shared__ __align__(16) _Float16 hbuf[2][320];        // skewed h, dbuf
    __shared__ __align__(16) _Float16 xzs[2][8][256];      // xz block stage
    __shared__ __align__(16) float    xhs[2][8][256];      // xh block stage

    // ---- U slices -> registers (64 VGPRs) ----
    hf2 uz[32], uh[32];
    {
        const float* pz = Uz + (size_t)og * HID + q * 64;
        const float* ph = Uh + (size_t)og * HID + q * 64;
#pragma unroll
        for (int i = 0; i < 16; ++i) {
            float4 v;
            v = *reinterpret_cast<const float4*>(pz + 4 * i);
            uz[2*i]   = hf2{(_Float16)v.x, (_Float16)v.y};
            uz[2*i+1] = hf2{(_Float16)v.z, (_Float16)v.w};
            v = *reinterpret_cast<const float4*>(ph + 4 * i);
            uh[2*i]   = hf2{(_Float16)v.x, (_Float16)v.y};
            uh[2*i+1] = hf2{(_Float16)v.z, (_Float16)v.w};
        }
    }

    // ---- init LDS h (skewed) + fp32 h state (replicated across q) ----
    if (tid < 256) {
        hbuf[0][tid + (tid >> 5) * 8] = (_Float16)hidden0[b * HID + tid];
    }
    float hp = hidden0[b * HID + og];
    float* pst = out + (size_t)b * HID + og;
    const int og_sk = og + (og >> 5) * 8;     // skewed write address for h

    // ---- x-staging: thread (srow, 2-elem chunk) ----
    const int srow = tid >> 7;           // 0..7 (step within block)
    const int scol = (tid & 127) * 2;    // 2-elem chunk
    hf2   rz;
    f32x2 rh;
    {
        const size_t a0 = ((size_t)srow * BATCH + b) * HID + scol;
        *reinterpret_cast<hf2*>(&xzs[0][srow][scol]) =
            *reinterpret_cast<const hf2*>(xz16 + a0);
        *reinterpret_cast<f32x2*>(&xhs[0][srow][scol]) =
            *reinterpret_cast<const f32x2*>(out + a0);
        const size_t a1 = ((size_t)(8 + srow) * BATCH + b) * HID + scol;
        rz = *reinterpret_cast<const hf2*>(xz16 + a1);
        rh = *reinterpret_cast<const f32x2*>(out + a1);
    }
    __syncthreads();

    for (int j = 0; j < NBLK; ++j) {
        const int jb = j & 1;
#pragma unroll
        for (int s = 0; s < 8; ++s) {
            // staged x reads (broadcast per og-group)
            const float xzc = (float)xzs[jb][s][og];
            const float xhc = xhs[jb][s][og];
            // matvec slice: 64 dot2, 4 independent chains; skewed base q*80
            const _Float16* hsl = &hbuf[s & 1][q * 80];
            float za = 0.f, zb = 0.f, ha = 0.f, hb = 0.f;
#pragma unroll
            for (int c8 = 0; c8 < 8; ++c8) {
                const int off = 8 * c8 + ((c8 >> 2) << 3);   // skip skew gap
                const hf8 hv = *reinterpret_cast<const hf8*>(hsl + off);
                const hf2 p0 = __builtin_shufflevector(hv, hv, 0, 1);
                const hf2 p1 = __builtin_shufflevector(hv, hv, 2, 3);
                const hf2 p2 = __builtin_shufflevector(hv, hv, 4, 5);
                const hf2 p3 = __builtin_shufflevector(hv, hv, 6, 7);
                if (c8 & 1) {
                    zb = dot2(p0, uz[4*c8+0], zb);
                    zb = dot2(p1, uz[4*c8+1], zb);
                    zb = dot2(p2, uz[4*c8+2], zb);
                    zb = dot2(p3, uz[4*c8+3], zb);
                    hb = dot2(p0, uh[4*c8+0], hb);
                    hb = dot2(p1, uh[4*c8+1], hb);
                    hb = dot2(p2, uh[4*c8+2], hb);
                    hb = dot2(p3, uh[4*c8+3], hb);
                } else {
                    za = dot2(p0, uz[4*c8+0], za);
                    za = dot2(p1, uz[4*c8+1], za);
                    za = dot2(p2, uz[4*c8+2], za);
                    za = dot2(p3, uz[4*c8+3], za);
                    ha = dot2(p0, uh[4*c8+0], ha);
                    ha = dot2(p1, uh[4*c8+1], ha);
                    ha = dot2(p2, uh[4*c8+2], ha);
                    ha = dot2(p3, uh[4*c8+3], ha);
                }
            }
            float accz = za + zb;
            float acch = ha + hb;
            // reduce over the 4 q-lanes (DPP butterfly)
            accz += __shfl_xor(accz, 1);
            accz += __shfl_xor(accz, 2);
            acch += __shfl_xor(acch, 1);
            acch += __shfl_xor(acch, 2);
            // epilogue: all q-lanes compute (replicated), q==0 stores
            const float z  = fast_sigmoid(accz + xzc);
            const float th = fast_tanh(acch + xhc);
            hp = fmaf(z, th - hp, hp);
            if (q == 0) {
                *pst = hp;                       // fire-and-forget HBM store
                hbuf[(s + 1) & 1][og_sk] = (_Float16)hp;
            }
            pst += (size_t)BATCH * HID;
            // block boundary: relay regs -> LDS, issue loads 2 blocks ahead
            if (s == 7 && j + 1 < NBLK) {
                *reinterpret_cast<hf2*>(&xzs[jb ^ 1][srow][scol])   = rz;
                *reinterpret_cast<f32x2*>(&xhs[jb ^ 1][srow][scol]) = rh;
                int trow = 8 * (j + 2) + srow;
                if (trow >= SEQ) trow = SEQ - 1;     // tail clamp (unused)
                const size_t an = ((size_t)trow * BATCH + b) * HID + scol;
                rz = *reinterpret_cast<const hf2*>(xz16 + an);
                rh = *reinterpret_cast<const f32x2*>(out + an);
            }
            bar_lds();
        }
    }

    if (q == 0) {
        h_final[(size_t)b * HID + og] = hp;
    }
}

extern "C" void kernel_launch(void* const* d_in, const int* in_sizes, int n_in,
                              void* d_out, int out_size, void* d_ws, size_t ws_size,
                              hipStream_t stream) {
    const float* x      = (const float*)d_in[0];
    const float* hidden = (const float*)d_in[1];
    const float* Wz     = (const float*)d_in[2];
    const float* bz     = (const float*)d_in[3];
    const float* Uz     = (const float*)d_in[4];
    const float* cz     = (const float*)d_in[5];
    const float* Wh     = (const float*)d_in[6];
    const float* bh     = (const float*)d_in[7];
    const float* Uh     = (const float*)d_in[8];
    const float* ch     = (const float*)d_in[9];

    float* out     = (float*)d_out;                        // [SEQ*BATCH*HID]
    float* h_final = out + (size_t)SEQ * BATCH * HID;      // [BATCH*HID]

    _Float16* xz16 = (_Float16*)d_ws;                               // 64 MiB
    _Float16* W16  = (_Float16*)((char*)d_ws + ((size_t)64 << 20)); // 256 KiB

    w16_kernel<<<512, 256, 0, stream>>>(Wz, Wh, W16);

    proj_mfma_kernel<<<(SEQ * BATCH) / 16, 256, 0, stream>>>(
        x, W16, bz, cz, bh, ch, xz16, out);

    rec_dot2_kernel<<<BATCH, 1024, 0, stream>>>(
        hidden, Uz, Uh, xz16, out, h_final);
}

// Round 18
// 2052.040 us; speedup vs baseline: 1.1062x; 1.0814x over previous
//
#include <hip/hip_runtime.h>
#include <math.h>

#define SEQ   2048
#define BATCH 64
#define IN    256
#define HID   256
#define NBLK  (SEQ / 8)

typedef _Float16 hf2 __attribute__((ext_vector_type(2)));
typedef _Float16 hf4 __attribute__((ext_vector_type(4)));
typedef _Float16 hf8 __attribute__((ext_vector_type(8)));
typedef float    f32x2 __attribute__((ext_vector_type(2)));
typedef float    f32x4 __attribute__((ext_vector_type(4)));

static __device__ __forceinline__ float dot2(hf2 a, hf2 b, float c) {
#if __has_builtin(__builtin_amdgcn_fdot2)
    return __builtin_amdgcn_fdot2(a, b, c, false);
#else
    return fmaf((float)a.x, (float)b.x, fmaf((float)a.y, (float)b.y, c));
#endif
}

// v += v permuted within 4-lane quads via DPP (full-rate VALU, no LDS pipe —
// __shfl_xor compiles to ds_bpermute_b32: LDS op + ~120cy lgkm latency).
// CTRL is a template param: __builtin_amdgcn_update_dpp requires an ICE.
// xor1 = quad_perm[1,0,3,2] = 0xB1 ; xor2 = quad_perm[2,3,0,1] = 0x4E.
template <int CTRL>
static __device__ __forceinline__ float dpp_add(float v) {
    const int pv = __builtin_amdgcn_update_dpp(
        0, __builtin_bit_cast(int, v), CTRL, 0xF, 0xF, true);
    return v + __builtin_bit_cast(float, pv);
}

static __device__ __forceinline__ float fast_sigmoid(float x) {
    return __builtin_amdgcn_rcpf(1.0f + __expf(-x));
}

static __device__ __forceinline__ float fast_tanh(float x) {
    const float e = __expf(-2.0f * x);
    return fmaf(2.0f, __builtin_amdgcn_rcpf(1.0f + e), -1.0f);
}

static __device__ __forceinline__ hf8 cvt8(const float4& a, const float4& b) {
    hf8 f;
    f[0] = (_Float16)a.x; f[1] = (_Float16)a.y;
    f[2] = (_Float16)a.z; f[3] = (_Float16)a.w;
    f[4] = (_Float16)b.x; f[5] = (_Float16)b.y;
    f[6] = (_Float16)b.z; f[7] = (_Float16)b.w;
    return f;
}

// LDS-ordering barrier: no vmcnt(0) drain (R13 win), no sched_barrier pin.
static __device__ __forceinline__ void bar_lds() {
    asm volatile("s_waitcnt lgkmcnt(0)" ::: "memory");
    __builtin_amdgcn_s_barrier();
}

// ---------------------------------------------------------------------------
// Kernel 0: Wz,Wh fp32 -> W16 [512][256] fp16
// ---------------------------------------------------------------------------
__global__ __launch_bounds__(256) void w16_kernel(
    const float* __restrict__ Wz, const float* __restrict__ Wh,
    _Float16* __restrict__ W16)
{
    const int idx = blockIdx.x * 256 + threadIdx.x;
    const int row = idx >> 8;
    const int col = idx & 255;
    const float v = (row < 256) ? Wz[row * 256 + col] : Wh[(row - 256) * 256 + col];
    W16[idx] = (_Float16)v;
}

// ---------------------------------------------------------------------------
// Kernel A: input projections via mfma_f32_16x16x32_f16 (validated R4+).
// ---------------------------------------------------------------------------
__global__ __launch_bounds__(256) void proj_mfma_kernel(
    const float* __restrict__ x,
    const _Float16* __restrict__ W16,
    const float* __restrict__ bz, const float* __restrict__ cz,
    const float* __restrict__ bh, const float* __restrict__ ch,
    _Float16* __restrict__ xz16,
    float* __restrict__ xh_out)
{
    const int tid  = threadIdx.x;
    const int lane = tid & 63;
    const int w    = tid >> 6;
    const int m0   = blockIdx.x * 16;
    const int col0 = w * 128;

    const int r = lane & 15;
    const int g = lane >> 4;

    f32x4 acc[8] = {f32x4{0,0,0,0}, f32x4{0,0,0,0}, f32x4{0,0,0,0}, f32x4{0,0,0,0},
                    f32x4{0,0,0,0}, f32x4{0,0,0,0}, f32x4{0,0,0,0}, f32x4{0,0,0,0}};

    const float*    xrow  = x   + (size_t)(m0 + r) * IN + g * 8;
    const _Float16* wbase = W16 + (size_t)(col0 + r) * IN + g * 8;

#pragma unroll
    for (int kt = 0; kt < 8; ++kt) {
        const float4 xa = *reinterpret_cast<const float4*>(xrow + kt * 32);
        const float4 xb = *reinterpret_cast<const float4*>(xrow + kt * 32 + 4);
        const hf8 a = cvt8(xa, xb);
#pragma unroll
        for (int t = 0; t < 8; ++t) {
            const hf8 bfrag = *reinterpret_cast<const hf8*>(
                wbase + (size_t)t * 16 * IN + kt * 32);
            acc[t] = __builtin_amdgcn_mfma_f32_16x16x32_f16(a, bfrag, acc[t], 0, 0, 0);
        }
    }

    if (w < 2) {
#pragma unroll
        for (int t = 0; t < 8; ++t) {
            const int c = col0 + t * 16 + r;
            const float bsum = bz[c] + cz[c];
#pragma unroll
            for (int reg = 0; reg < 4; ++reg) {
                const int m = m0 + 4 * g + reg;
                xz16[(size_t)m * HID + c] = (_Float16)(acc[t][reg] + bsum);
            }
        }
    } else {
#pragma unroll
        for (int t = 0; t < 8; ++t) {
            const int c = col0 - 256 + t * 16 + r;
            const float bsum = bh[c] + ch[c];
#pragma unroll
            for (int reg = 0; reg < 4; ++reg) {
                const int m = m0 + 4 * g + reg;
                xh_out[(size_t)m * HID + c] = acc[t][reg] + bsum;
            }
        }
    }
}

// ---------------------------------------------------------------------------
// Kernel B: dot2 (VALU) recurrence, R16 structure with ONE change (R17/R18):
// the q-reduce butterfly uses DPP quad_perm adds instead of __shfl_xor
// (which compiles to ds_bpermute_b32 = LDS pipe + ~120cy latency, 2-deep
// -> ~240cy exposed serial per step + 4 LDS ops/thread).
// Everything else identical: one WG/batch, 1024 thr (4 waves/SIMD), 64
// dot2/thread, skewed h LDS (0 conflicts, R16-verified), all-lane fast
// epilogue with q==0 stores, LDS x-block staging, lgkm-only barrier.
// ---------------------------------------------------------------------------
__global__ __launch_bounds__(1024, 1) void rec_dot2_kernel(
    const float* __restrict__ hidden0,
    const float* __restrict__ Uz,
    const float* __restrict__ Uh,
    const _Float16* __restrict__ xz16,
    float* __restrict__ out,
    float* __restrict__ h_final)
{
    const int b   = blockIdx.x;         // batch element (one per WG)
    const int tid = threadIdx.x;
    const int og  = tid >> 2;           // output 0..255
    const int q   = tid & 3;            // k-slice 0..3

    __shared__ __align__(16) _Float16 hbuf[2][320];        // skewed h, dbuf
    __shared__ __align__(16) _Float16 xzs[2][8][256];      // xz block stage
    __shared__ __align__(16) float    xhs[2][8][256];      // xh block stage

    // ---- U slices -> registers (64 VGPRs) ----
    hf2 uz[32], uh[32];
    {
        const float* pz = Uz + (size_t)og * HID + q * 64;
        const float* ph = Uh + (size_t)og * HID + q * 64;
#pragma unroll
        for (int i = 0; i < 16; ++i) {
            float4 v;
            v = *reinterpret_cast<const float4*>(pz + 4 * i);
            uz[2*i]   = hf2{(_Float16)v.x, (_Float16)v.y};
            uz[2*i+1] = hf2{(_Float16)v.z, (_Float16)v.w};
            v = *reinterpret_cast<const float4*>(ph + 4 * i);
            uh[2*i]   = hf2{(_Float16)v.x, (_Float16)v.y};
            uh[2*i+1] = hf2{(_Float16)v.z, (_Float16)v.w};
        }
    }

    // ---- init LDS h (skewed) + fp32 h state (replicated across q) ----
    if (tid < 256) {
        hbuf[0][tid + (tid >> 5) * 8] = (_Float16)hidden0[b * HID + tid];
    }
    float hp = hidden0[b * HID + og];
    float* pst = out + (size_t)b * HID + og;
    const int og_sk = og + (og >> 5) * 8;     // skewed write address for h

    // ---- x-staging: thread (srow, 2-elem chunk) ----
    const int srow = tid >> 7;           // 0..7 (step within block)
    const int scol = (tid & 127) * 2;    // 2-elem chunk
    hf2   rz;
    f32x2 rh;
    {
        const size_t a0 = ((size_t)srow * BATCH + b) * HID + scol;
        *reinterpret_cast<hf2*>(&xzs[0][srow][scol]) =
            *reinterpret_cast<const hf2*>(xz16 + a0);
        *reinterpret_cast<f32x2*>(&xhs[0][srow][scol]) =
            *reinterpret_cast<const f32x2*>(out + a0);
        const size_t a1 = ((size_t)(8 + srow) * BATCH + b) * HID + scol;
        rz = *reinterpret_cast<const hf2*>(xz16 + a1);
        rh = *reinterpret_cast<const f32x2*>(out + a1);
    }
    __syncthreads();

    for (int j = 0; j < NBLK; ++j) {
        const int jb = j & 1;
#pragma unroll
        for (int s = 0; s < 8; ++s) {
            // staged x reads (broadcast per og-group)
            const float xzc = (float)xzs[jb][s][og];
            const float xhc = xhs[jb][s][og];
            // matvec slice: 64 dot2, 4 independent chains; skewed base q*80
            const _Float16* hsl = &hbuf[s & 1][q * 80];
            float za = 0.f, zb = 0.f, ha = 0.f, hb = 0.f;
#pragma unroll
            for (int c8 = 0; c8 < 8; ++c8) {
                const int off = 8 * c8 + ((c8 >> 2) << 3);   // skip skew gap
                const hf8 hv = *reinterpret_cast<const hf8*>(hsl + off);
                const hf2 p0 = __builtin_shufflevector(hv, hv, 0, 1);
                const hf2 p1 = __builtin_shufflevector(hv, hv, 2, 3);
                const hf2 p2 = __builtin_shufflevector(hv, hv, 4, 5);
                const hf2 p3 = __builtin_shufflevector(hv, hv, 6, 7);
                if (c8 & 1) {
                    zb = dot2(p0, uz[4*c8+0], zb);
                    zb = dot2(p1, uz[4*c8+1], zb);
                    zb = dot2(p2, uz[4*c8+2], zb);
                    zb = dot2(p3, uz[4*c8+3], zb);
                    hb = dot2(p0, uh[4*c8+0], hb);
                    hb = dot2(p1, uh[4*c8+1], hb);
                    hb = dot2(p2, uh[4*c8+2], hb);
                    hb = dot2(p3, uh[4*c8+3], hb);
                } else {
                    za = dot2(p0, uz[4*c8+0], za);
                    za = dot2(p1, uz[4*c8+1], za);
                    za = dot2(p2, uz[4*c8+2], za);
                    za = dot2(p3, uz[4*c8+3], za);
                    ha = dot2(p0, uh[4*c8+0], ha);
                    ha = dot2(p1, uh[4*c8+1], ha);
                    ha = dot2(p2, uh[4*c8+2], ha);
                    ha = dot2(p3, uh[4*c8+3], ha);
                }
            }
            float accz = za + zb;
            float acch = ha + hb;
            // reduce over the 4 q-lanes: DPP quad_perm butterfly (VALU-only)
            accz = dpp_add<0xB1>(accz);   // += lane^1
            acch = dpp_add<0xB1>(acch);
            accz = dpp_add<0x4E>(accz);   // += lane^2
            acch = dpp_add<0x4E>(acch);
            // epilogue: all q-lanes compute (replicated), q==0 stores
            const float z  = fast_sigmoid(accz + xzc);
            const float th = fast_tanh(acch + xhc);
            hp = fmaf(z, th - hp, hp);
            if (q == 0) {
                *pst = hp;                       // fire-and-forget HBM store
                hbuf[(s + 1) & 1][og_sk] = (_Float16)hp;
            }
            pst += (size_t)BATCH * HID;
            // block boundary: relay regs -> LDS, issue loads 2 blocks ahead
            if (s == 7 && j + 1 < NBLK) {
                *reinterpret_cast<hf2*>(&xzs[jb ^ 1][srow][scol])   = rz;
                *reinterpret_cast<f32x2*>(&xhs[jb ^ 1][srow][scol]) = rh;
                int trow = 8 * (j + 2) + srow;
                if (trow >= SEQ) trow = SEQ - 1;     // tail clamp (unused)
                const size_t an = ((size_t)trow * BATCH + b) * HID + scol;
                rz = *reinterpret_cast<const hf2*>(xz16 + an);
                rh = *reinterpret_cast<const f32x2*>(out + an);
            }
            bar_lds();
        }
    }

    if (q == 0) {
        h_final[(size_t)b * HID + og] = hp;
    }
}

extern "C" void kernel_launch(void* const* d_in, const int* in_sizes, int n_in,
                              void* d_out, int out_size, void* d_ws, size_t ws_size,
                              hipStream_t stream) {
    const float* x      = (const float*)d_in[0];
    const float* hidden = (const float*)d_in[1];
    const float* Wz     = (const float*)d_in[2];
    const float* bz     = (const float*)d_in[3];
    const float* Uz     = (const float*)d_in[4];
    const float* cz     = (const float*)d_in[5];
    const float* Wh     = (const float*)d_in[6];
    const float* bh     = (const float*)d_in[7];
    const float* Uh     = (const float*)d_in[8];
    const float* ch     = (const float*)d_in[9];

    float* out     = (float*)d_out;                        // [SEQ*BATCH*HID]
    float* h_final = out + (size_t)SEQ * BATCH * HID;      // [BATCH*HID]

    _Float16* xz16 = (_Float16*)d_ws;                               // 64 MiB
    _Float16* W16  = (_Float16*)((char*)d_ws + ((size_t)64 << 20)); // 256 KiB

    w16_kernel<<<512, 256, 0, stream>>>(Wz, Wh, W16);

    proj_mfma_kernel<<<(SEQ * BATCH) / 16, 256, 0, stream>>>(
        x, W16, bz, cz, bh, ch, xz16, out);

    rec_dot2_kernel<<<BATCH, 1024, 0, stream>>>(
        hidden, Uz, Uh, xz16, out, h_final);
}

// Round 19
// 2039.228 us; speedup vs baseline: 1.1131x; 1.0063x over previous
//
#include <hip/hip_runtime.h>
#include <math.h>

#define SEQ   2048
#define BATCH 64
#define IN    256
#define HID   256
#define NBLK  (SEQ / 8)

typedef _Float16 hf2 __attribute__((ext_vector_type(2)));
typedef _Float16 hf4 __attribute__((ext_vector_type(4)));
typedef _Float16 hf8 __attribute__((ext_vector_type(8)));
typedef float    f32x2 __attribute__((ext_vector_type(2)));
typedef float    f32x4 __attribute__((ext_vector_type(4)));

static __device__ __forceinline__ float dot2(hf2 a, hf2 b, float c) {
#if __has_builtin(__builtin_amdgcn_fdot2)
    return __builtin_amdgcn_fdot2(a, b, c, false);
#else
    return fmaf((float)a.x, (float)b.x, fmaf((float)a.y, (float)b.y, c));
#endif
}

// DPP quad_perm butterfly add (VALU-only; R18-verified).
template <int CTRL>
static __device__ __forceinline__ float dpp_add(float v) {
    const int pv = __builtin_amdgcn_update_dpp(
        0, __builtin_bit_cast(int, v), CTRL, 0xF, 0xF, true);
    return v + __builtin_bit_cast(float, pv);
}

static __device__ __forceinline__ float fast_sigmoid(float x) {
    return __builtin_amdgcn_rcpf(1.0f + __expf(-x));
}

static __device__ __forceinline__ float fast_tanh(float x) {
    const float e = __expf(-2.0f * x);
    return fmaf(2.0f, __builtin_amdgcn_rcpf(1.0f + e), -1.0f);
}

static __device__ __forceinline__ hf8 cvt8(const float4& a, const float4& b) {
    hf8 f;
    f[0] = (_Float16)a.x; f[1] = (_Float16)a.y;
    f[2] = (_Float16)a.z; f[3] = (_Float16)a.w;
    f[4] = (_Float16)b.x; f[5] = (_Float16)b.y;
    f[6] = (_Float16)b.z; f[7] = (_Float16)b.w;
    return f;
}

// LDS-ordering barrier: no vmcnt(0) drain (R13 win).
static __device__ __forceinline__ void bar_lds() {
    asm volatile("s_waitcnt lgkmcnt(0)" ::: "memory");
    __builtin_amdgcn_s_barrier();
}

// ---------------------------------------------------------------------------
// Kernel 0: Wz,Wh fp32 -> W16 [512][256] fp16
// ---------------------------------------------------------------------------
__global__ __launch_bounds__(256) void w16_kernel(
    const float* __restrict__ Wz, const float* __restrict__ Wh,
    _Float16* __restrict__ W16)
{
    const int idx = blockIdx.x * 256 + threadIdx.x;
    const int row = idx >> 8;
    const int col = idx & 255;
    const float v = (row < 256) ? Wz[row * 256 + col] : Wh[(row - 256) * 256 + col];
    W16[idx] = (_Float16)v;
}

// ---------------------------------------------------------------------------
// Kernel A: input projections via mfma_f32_16x16x32_f16 (validated R4+).
// ---------------------------------------------------------------------------
__global__ __launch_bounds__(256) void proj_mfma_kernel(
    const float* __restrict__ x,
    const _Float16* __restrict__ W16,
    const float* __restrict__ bz, const float* __restrict__ cz,
    const float* __restrict__ bh, const float* __restrict__ ch,
    _Float16* __restrict__ xz16,
    float* __restrict__ xh_out)
{
    const int tid  = threadIdx.x;
    const int lane = tid & 63;
    const int w    = tid >> 6;
    const int m0   = blockIdx.x * 16;
    const int col0 = w * 128;

    const int r = lane & 15;
    const int g = lane >> 4;

    f32x4 acc[8] = {f32x4{0,0,0,0}, f32x4{0,0,0,0}, f32x4{0,0,0,0}, f32x4{0,0,0,0},
                    f32x4{0,0,0,0}, f32x4{0,0,0,0}, f32x4{0,0,0,0}, f32x4{0,0,0,0}};

    const float*    xrow  = x   + (size_t)(m0 + r) * IN + g * 8;
    const _Float16* wbase = W16 + (size_t)(col0 + r) * IN + g * 8;

#pragma unroll
    for (int kt = 0; kt < 8; ++kt) {
        const float4 xa = *reinterpret_cast<const float4*>(xrow + kt * 32);
        const float4 xb = *reinterpret_cast<const float4*>(xrow + kt * 32 + 4);
        const hf8 a = cvt8(xa, xb);
#pragma unroll
        for (int t = 0; t < 8; ++t) {
            const hf8 bfrag = *reinterpret_cast<const hf8*>(
                wbase + (size_t)t * 16 * IN + kt * 32);
            acc[t] = __builtin_amdgcn_mfma_f32_16x16x32_f16(a, bfrag, acc[t], 0, 0, 0);
        }
    }

    if (w < 2) {
#pragma unroll
        for (int t = 0; t < 8; ++t) {
            const int c = col0 + t * 16 + r;
            const float bsum = bz[c] + cz[c];
#pragma unroll
            for (int reg = 0; reg < 4; ++reg) {
                const int m = m0 + 4 * g + reg;
                xz16[(size_t)m * HID + c] = (_Float16)(acc[t][reg] + bsum);
            }
        }
    } else {
#pragma unroll
        for (int t = 0; t < 8; ++t) {
            const int c = col0 - 256 + t * 16 + r;
            const float bsum = bh[c] + ch[c];
#pragma unroll
            for (int reg = 0; reg < 4; ++reg) {
                const int m = m0 + 4 * g + reg;
                xh_out[(size_t)m * HID + c] = acc[t][reg] + bsum;
            }
        }
    }
}

// ---------------------------------------------------------------------------
// Kernel B (R19): WAVE-SPECIALIZED HYBRID. One WG/batch, 1024 thr, 16 waves.
//   Waves 0-7 ("M"): R14 broadcast-MFMA for outputs 0-127 (matrix pipe).
//   Waves 8-15 ("V"): R18 dot2 for outputs 128-255 (VALU pipe).
// Each SIMD gets 2 M + 2 V waves -> both pipes busy concurrently (m114).
// Unified register file: hf8 ureg[16] (64 VGPRs) loaded divergently —
//   M: ureg[kt]/ureg[8+kt] = A-fragments of tiles 2w / 2w+1 (interleaved U).
//   V: ureg[c8]/ureg[8+c8] = Uz/Uh row og, halves [64q+8c8, +8) (hf2
//      extracts are free register sub-selects).
// h published to TWO LDS copies: linear (M's uniform bb reads) + skewed
// (V's conflict-free b128). Both write patterns <=2 lanes/bank (free).
// Retained: LDS x-block staging, lgkm-only barrier, DPP reduce,
// lane-redistributed epilogues, fire-and-forget h stores.
// ---------------------------------------------------------------------------
__global__ __launch_bounds__(1024, 1) void rec_hybrid_kernel(
    const float* __restrict__ hidden0,
    const float* __restrict__ Uz,
    const float* __restrict__ Uh,
    const _Float16* __restrict__ xz16,
    float* __restrict__ out,
    float* __restrict__ h_final)
{
    const int b    = blockIdx.x;
    const int tid  = threadIdx.x;
    const int w    = tid >> 6;          // wave 0..15
    const int lane = tid & 63;
    const bool m_wave = (w < 8);

    // M-wave roles
    const int r = lane & 15;            // A-row in tile / D col (replica)
    const int g = lane >> 4;            // k-group / reg-group
    // V-wave roles
    const int q   = lane & 3;           // k-slice 0..3
    const int vog = 128 + (w - 8) * 16 + (lane >> 2);   // V output (w>=8)

    __shared__ __align__(16) _Float16 hlin[2][256];     // linear h (M reads)
    __shared__ __align__(16) _Float16 hsk[2][320];      // skewed h (V reads)
    __shared__ __align__(16) float    sbuf[256];        // M preact exchange
    __shared__ __align__(16) _Float16 xzs[2][8][256];   // xz block stage
    __shared__ __align__(16) float    xhs[2][8][256];   // xh block stage

    // ---- unified U registers (64 VGPRs), loaded per wave class ----
    hf8 ureg[16];
    if (m_wave) {
        // tiles 2w (->ureg[0..7]) and 2w+1 (->ureg[8..15]);
        // interleaved row 16m+r <-> (r&1 ? Uh : Uz)[8m + (r>>1)]
        const float* usrc = (r & 1) ? Uh : Uz;
        const int    hrow = r >> 1;
#pragma unroll
        for (int i = 0; i < 2; ++i) {
            const int m = 2 * w + i;
            const float* p0 = usrc + (size_t)(8 * m + hrow) * HID;
#pragma unroll
            for (int kt = 0; kt < 8; ++kt) {
                const float* p = p0 + kt * 32 + 8 * g;
                ureg[8 * i + kt] = cvt8(*reinterpret_cast<const float4*>(p),
                                        *reinterpret_cast<const float4*>(p + 4));
            }
        }
    } else {
        // Uz row vog (->ureg[0..7]), Uh row vog (->ureg[8..15]), slice q
        const float* pz = Uz + (size_t)vog * HID + q * 64;
        const float* ph = Uh + (size_t)vog * HID + q * 64;
#pragma unroll
        for (int c8 = 0; c8 < 8; ++c8) {
            ureg[c8]     = cvt8(*reinterpret_cast<const float4*>(pz + 8 * c8),
                                *reinterpret_cast<const float4*>(pz + 8 * c8 + 4));
            ureg[8 + c8] = cvt8(*reinterpret_cast<const float4*>(ph + 8 * c8),
                                *reinterpret_cast<const float4*>(ph + 8 * c8 + 4));
        }
    }

    // ---- init LDS h (both copies) ----
    if (tid < 256) {
        const _Float16 h0 = (_Float16)hidden0[b * HID + tid];
        hlin[0][tid] = h0;
        hsk[0][tid + (tid >> 5) * 8] = h0;
    }

    // ---- per-class epilogue state ----
    const int mo = 16 * w + (lane & 15);          // M output (lane<16, w<8)
    const int own_o = m_wave ? mo : vog;          // this thread's output
    float hp = hidden0[b * HID + (own_o & 255)];
    float* pst = out + (size_t)b * HID + own_o;
    const int osk = own_o + (own_o >> 5) * 8;     // skewed write addr

    // ---- x-staging: thread (srow, 2-elem chunk) ----
    const int srow = tid >> 7;
    const int scol = (tid & 127) * 2;
    hf2   rz;
    f32x2 rh;
    {
        const size_t a0 = ((size_t)srow * BATCH + b) * HID + scol;
        *reinterpret_cast<hf2*>(&xzs[0][srow][scol]) =
            *reinterpret_cast<const hf2*>(xz16 + a0);
        *reinterpret_cast<f32x2*>(&xhs[0][srow][scol]) =
            *reinterpret_cast<const f32x2*>(out + a0);
        const size_t a1 = ((size_t)(8 + srow) * BATCH + b) * HID + scol;
        rz = *reinterpret_cast<const hf2*>(xz16 + a1);
        rh = *reinterpret_cast<const f32x2*>(out + a1);
    }
    __syncthreads();

#define UE(ri, e) __builtin_shufflevector(ureg[ri], ureg[ri], 2*(e), 2*(e)+1)

    for (int j = 0; j < NBLK; ++j) {
        const int jb = j & 1;
#pragma unroll
        for (int s = 0; s < 8; ++s) {
            if (m_wave) {
                const float xzc = (float)xzs[jb][s][mo];
                const float xhc = xhs[jb][s][mo];
                f32x4 acc0{0, 0, 0, 0}, acc1{0, 0, 0, 0};
#pragma unroll
                for (int kt = 0; kt < 8; ++kt) {
                    const hf8 bb = *reinterpret_cast<const hf8*>(
                        &hlin[s & 1][kt * 32 + 8 * g]);
                    acc0 = __builtin_amdgcn_mfma_f32_16x16x32_f16(
                        ureg[kt], bb, acc0, 0, 0, 0);
                    acc1 = __builtin_amdgcn_mfma_f32_16x16x32_f16(
                        ureg[8 + kt], bb, acc1, 0, 0, 0);
                }
                if (r == 0) {
                    *reinterpret_cast<f32x4*>(&sbuf[(2 * w) * 16 + 4 * g])     = acc0;
                    *reinterpret_cast<f32x4*>(&sbuf[(2 * w + 1) * 16 + 4 * g]) = acc1;
                }
                if (lane < 16) {
                    const f32x2 pr = *reinterpret_cast<const f32x2*>(&sbuf[2 * mo]);
                    const float z  = fast_sigmoid(pr[0] + xzc);
                    const float th = fast_tanh(pr[1] + xhc);
                    hp = fmaf(z, th - hp, hp);
                    *pst = hp;
                    const _Float16 hh = (_Float16)hp;
                    hlin[(s + 1) & 1][mo] = hh;
                    hsk[(s + 1) & 1][osk] = hh;
                }
            } else {
                const float xzc = (float)xzs[jb][s][vog];
                const float xhc = xhs[jb][s][vog];
                const _Float16* hsl = &hsk[s & 1][q * 80];
                float za = 0.f, zb = 0.f, ha = 0.f, hb = 0.f;
#pragma unroll
                for (int c8 = 0; c8 < 8; ++c8) {
                    const int off = 8 * c8 + ((c8 >> 2) << 3);
                    const hf8 hv = *reinterpret_cast<const hf8*>(hsl + off);
                    const hf2 p0 = __builtin_shufflevector(hv, hv, 0, 1);
                    const hf2 p1 = __builtin_shufflevector(hv, hv, 2, 3);
                    const hf2 p2 = __builtin_shufflevector(hv, hv, 4, 5);
                    const hf2 p3 = __builtin_shufflevector(hv, hv, 6, 7);
                    if (c8 & 1) {
                        zb = dot2(p0, UE(c8, 0), zb);
                        zb = dot2(p1, UE(c8, 1), zb);
                        zb = dot2(p2, UE(c8, 2), zb);
                        zb = dot2(p3, UE(c8, 3), zb);
                        hb = dot2(p0, UE(8 + c8, 0), hb);
                        hb = dot2(p1, UE(8 + c8, 1), hb);
                        hb = dot2(p2, UE(8 + c8, 2), hb);
                        hb = dot2(p3, UE(8 + c8, 3), hb);
                    } else {
                        za = dot2(p0, UE(c8, 0), za);
                        za = dot2(p1, UE(c8, 1), za);
                        za = dot2(p2, UE(c8, 2), za);
                        za = dot2(p3, UE(c8, 3), za);
                        ha = dot2(p0, UE(8 + c8, 0), ha);
                        ha = dot2(p1, UE(8 + c8, 1), ha);
                        ha = dot2(p2, UE(8 + c8, 2), ha);
                        ha = dot2(p3, UE(8 + c8, 3), ha);
                    }
                }
                float accz = za + zb;
                float acch = ha + hb;
                accz = dpp_add<0xB1>(accz);
                acch = dpp_add<0xB1>(acch);
                accz = dpp_add<0x4E>(accz);
                acch = dpp_add<0x4E>(acch);
                const float z  = fast_sigmoid(accz + xzc);
                const float th = fast_tanh(acch + xhc);
                hp = fmaf(z, th - hp, hp);
                if (q == 0) {
                    *pst = hp;
                    const _Float16 hh = (_Float16)hp;
                    hlin[(s + 1) & 1][vog] = hh;
                    hsk[(s + 1) & 1][osk]  = hh;
                }
            }
            pst += (size_t)BATCH * HID;
            // block boundary: relay regs -> LDS, issue loads 2 blocks ahead
            if (s == 7 && j + 1 < NBLK) {
                *reinterpret_cast<hf2*>(&xzs[jb ^ 1][srow][scol])   = rz;
                *reinterpret_cast<f32x2*>(&xhs[jb ^ 1][srow][scol]) = rh;
                int trow = 8 * (j + 2) + srow;
                if (trow >= SEQ) trow = SEQ - 1;
                const size_t an = ((size_t)trow * BATCH + b) * HID + scol;
                rz = *reinterpret_cast<const hf2*>(xz16 + an);
                rh = *reinterpret_cast<const f32x2*>(out + an);
            }
            bar_lds();
        }
    }
#undef UE

    if ((m_wave && lane < 16) || (!m_wave && q == 0)) {
        h_final[(size_t)b * HID + own_o] = hp;
    }
}

extern "C" void kernel_launch(void* const* d_in, const int* in_sizes, int n_in,
                              void* d_out, int out_size, void* d_ws, size_t ws_size,
                              hipStream_t stream) {
    const float* x      = (const float*)d_in[0];
    const float* hidden = (const float*)d_in[1];
    const float* Wz     = (const float*)d_in[2];
    const float* bz     = (const float*)d_in[3];
    const float* Uz     = (const float*)d_in[4];
    const float* cz     = (const float*)d_in[5];
    const float* Wh     = (const float*)d_in[6];
    const float* bh     = (const float*)d_in[7];
    const float* Uh     = (const float*)d_in[8];
    const float* ch     = (const float*)d_in[9];

    float* out     = (float*)d_out;                        // [SEQ*BATCH*HID]
    float* h_final = out + (size_t)SEQ * BATCH * HID;      // [BATCH*HID]

    _Float16* xz16 = (_Float16*)d_ws;                               // 64 MiB
    _Float16* W16  = (_Float16*)((char*)d_ws + ((size_t)64 << 20)); // 256 KiB

    w16_kernel<<<512, 256, 0, stream>>>(Wz, Wh, W16);

    proj_mfma_kernel<<<(SEQ * BATCH) / 16, 256, 0, stream>>>(
        x, W16, bz, cz, bh, ch, xz16, out);

    rec_hybrid_kernel<<<BATCH, 1024, 0, stream>>>(
        hidden, Uz, Uh, xz16, out, h_final);
}

// Round 21
// 1909.015 us; speedup vs baseline: 1.1891x; 1.0682x over previous
//
#include <hip/hip_runtime.h>
#include <math.h>

#define SEQ   2048
#define BATCH 64
#define IN    256
#define HID   256
#define NBLK  (SEQ / 8)

typedef _Float16 hf2 __attribute__((ext_vector_type(2)));
typedef _Float16 hf4 __attribute__((ext_vector_type(4)));
typedef _Float16 hf8 __attribute__((ext_vector_type(8)));
typedef float    f32x2 __attribute__((ext_vector_type(2)));
typedef float    f32x4 __attribute__((ext_vector_type(4)));

static __device__ __forceinline__ float dot2(hf2 a, hf2 b, float c) {
#if __has_builtin(__builtin_amdgcn_fdot2)
    return __builtin_amdgcn_fdot2(a, b, c, false);
#else
    return fmaf((float)a.x, (float)b.x, fmaf((float)a.y, (float)b.y, c));
#endif
}

// DPP quad_perm butterfly add (VALU-only; R18-verified).
template <int CTRL>
static __device__ __forceinline__ float dpp_add(float v) {
    const int pv = __builtin_amdgcn_update_dpp(
        0, __builtin_bit_cast(int, v), CTRL, 0xF, 0xF, true);
    return v + __builtin_bit_cast(float, pv);
}

static __device__ __forceinline__ float fast_sigmoid(float x) {
    return __builtin_amdgcn_rcpf(1.0f + __expf(-x));
}

static __device__ __forceinline__ float fast_tanh(float x) {
    const float e = __expf(-2.0f * x);
    return fmaf(2.0f, __builtin_amdgcn_rcpf(1.0f + e), -1.0f);
}

static __device__ __forceinline__ hf8 cvt8(const float4& a, const float4& b) {
    hf8 f;
    f[0] = (_Float16)a.x; f[1] = (_Float16)a.y;
    f[2] = (_Float16)a.z; f[3] = (_Float16)a.w;
    f[4] = (_Float16)b.x; f[5] = (_Float16)b.y;
    f[6] = (_Float16)b.z; f[7] = (_Float16)b.w;
    return f;
}

// LDS-ordering barrier: no vmcnt(0) drain (R13 win).
static __device__ __forceinline__ void bar_lds() {
    asm volatile("s_waitcnt lgkmcnt(0)" ::: "memory");
    __builtin_amdgcn_s_barrier();
}

// ---------------------------------------------------------------------------
// Kernel 0: Wz,Wh fp32 -> W16 [512][256] fp16
// ---------------------------------------------------------------------------
__global__ __launch_bounds__(256) void w16_kernel(
    const float* __restrict__ Wz, const float* __restrict__ Wh,
    _Float16* __restrict__ W16)
{
    const int idx = blockIdx.x * 256 + threadIdx.x;
    const int row = idx >> 8;
    const int col = idx & 255;
    const float v = (row < 256) ? Wz[row * 256 + col] : Wh[(row - 256) * 256 + col];
    W16[idx] = (_Float16)v;
}

// ---------------------------------------------------------------------------
// Kernel A: input projections via mfma_f32_16x16x32_f16 (validated R4+).
// ---------------------------------------------------------------------------
__global__ __launch_bounds__(256) void proj_mfma_kernel(
    const float* __restrict__ x,
    const _Float16* __restrict__ W16,
    const float* __restrict__ bz, const float* __restrict__ cz,
    const float* __restrict__ bh, const float* __restrict__ ch,
    _Float16* __restrict__ xz16,
    float* __restrict__ xh_out)
{
    const int tid  = threadIdx.x;
    const int lane = tid & 63;
    const int w    = tid >> 6;
    const int m0   = blockIdx.x * 16;
    const int col0 = w * 128;

    const int r = lane & 15;
    const int g = lane >> 4;

    f32x4 acc[8] = {f32x4{0,0,0,0}, f32x4{0,0,0,0}, f32x4{0,0,0,0}, f32x4{0,0,0,0},
                    f32x4{0,0,0,0}, f32x4{0,0,0,0}, f32x4{0,0,0,0}, f32x4{0,0,0,0}};

    const float*    xrow  = x   + (size_t)(m0 + r) * IN + g * 8;
    const _Float16* wbase = W16 + (size_t)(col0 + r) * IN + g * 8;

#pragma unroll
    for (int kt = 0; kt < 8; ++kt) {
        const float4 xa = *reinterpret_cast<const float4*>(xrow + kt * 32);
        const float4 xb = *reinterpret_cast<const float4*>(xrow + kt * 32 + 4);
        const hf8 a = cvt8(xa, xb);
#pragma unroll
        for (int t = 0; t < 8; ++t) {
            const hf8 bfrag = *reinterpret_cast<const hf8*>(
                wbase + (size_t)t * 16 * IN + kt * 32);
            acc[t] = __builtin_amdgcn_mfma_f32_16x16x32_f16(a, bfrag, acc[t], 0, 0, 0);
        }
    }

    if (w < 2) {
#pragma unroll
        for (int t = 0; t < 8; ++t) {
            const int c = col0 + t * 16 + r;
            const float bsum = bz[c] + cz[c];
#pragma unroll
            for (int reg = 0; reg < 4; ++reg) {
                const int m = m0 + 4 * g + reg;
                xz16[(size_t)m * HID + c] = (_Float16)(acc[t][reg] + bsum);
            }
        }
    } else {
#pragma unroll
        for (int t = 0; t < 8; ++t) {
            const int c = col0 - 256 + t * 16 + r;
            const float bsum = bh[c] + ch[c];
#pragma unroll
            for (int reg = 0; reg < 4; ++reg) {
                const int m = m0 + 4 * g + reg;
                xh_out[(size_t)m * HID + c] = acc[t][reg] + bsum;
            }
        }
    }
}

// ---------------------------------------------------------------------------
// Kernel B (R21 = R20 with the skew-offset FIX): dot2 recurrence, 2 threads
// per output (512 thr, 8 waves).
// Skew addr(k) = k + (k>>5)*8 halves. Slice q covers k in [128q, 128q+128),
// base = 160q halves. Chunk i (8 halves at k_local = 8i) sits at slice
// offset 8i + 8*(i>>2)  [R20's 16i + 8*(i>>1) was a doubled stride: wrong
// data + OOB at i=15 -> absmax 0.945].
//   - U = 128 VGPRs (uz[64]+uh[64] hf2); __launch_bounds__(512,2): cap 256.
//   - 4 dot2 chains per matrix; ONE dpp xor1 reduce (lanes 2og <-> 2og+1).
//   - epilogue: both q-lanes compute (2x redundant), q==0 stores.
//   - retained: LDS x-block staging, lgkm-only barrier, fire-and-forget
//     h stores, skewed-conflict-free h reads (bases banks {0-3}/{16-19}).
// ---------------------------------------------------------------------------
__global__ __launch_bounds__(512, 2) void rec_dot2_kernel(
    const float* __restrict__ hidden0,
    const float* __restrict__ Uz,
    const float* __restrict__ Uh,
    const _Float16* __restrict__ xz16,
    float* __restrict__ out,
    float* __restrict__ h_final)
{
    const int b   = blockIdx.x;         // batch element (one per WG)
    const int tid = threadIdx.x;
    const int og  = tid >> 1;           // output 0..255
    const int q   = tid & 1;            // k-slice 0..1

    __shared__ __align__(16) _Float16 hbuf[2][320];        // skewed h, dbuf
    __shared__ __align__(16) _Float16 xzs[2][8][256];      // xz block stage
    __shared__ __align__(16) float    xhs[2][8][256];      // xh block stage

    // ---- U slices -> registers (128 VGPRs) ----
    hf2 uz[64], uh[64];
    {
        const float* pz = Uz + (size_t)og * HID + q * 128;
        const float* ph = Uh + (size_t)og * HID + q * 128;
#pragma unroll
        for (int i = 0; i < 32; ++i) {
            float4 v;
            v = *reinterpret_cast<const float4*>(pz + 4 * i);
            uz[2*i]   = hf2{(_Float16)v.x, (_Float16)v.y};
            uz[2*i+1] = hf2{(_Float16)v.z, (_Float16)v.w};
            v = *reinterpret_cast<const float4*>(ph + 4 * i);
            uh[2*i]   = hf2{(_Float16)v.x, (_Float16)v.y};
            uh[2*i+1] = hf2{(_Float16)v.z, (_Float16)v.w};
        }
    }

    // ---- init LDS h (skewed) + fp32 h state (replicated across q) ----
    if (tid < 256) {
        hbuf[0][tid + (tid >> 5) * 8] = (_Float16)hidden0[b * HID + tid];
    }
    float hp = hidden0[b * HID + og];
    float* pst = out + (size_t)b * HID + og;
    const int og_sk = og + (og >> 5) * 8;     // skewed write address for h

    // ---- x-staging: thread (srow, 4-elem chunk) ----
    const int srow = tid >> 6;           // 0..7 (step within block)
    const int scol = (tid & 63) * 4;     // 4-elem chunk
    hf4   rz;
    f32x4 rh;
    {
        const size_t a0 = ((size_t)srow * BATCH + b) * HID + scol;
        *reinterpret_cast<hf4*>(&xzs[0][srow][scol]) =
            *reinterpret_cast<const hf4*>(xz16 + a0);
        *reinterpret_cast<f32x4*>(&xhs[0][srow][scol]) =
            *reinterpret_cast<const f32x4*>(out + a0);
        const size_t a1 = ((size_t)(8 + srow) * BATCH + b) * HID + scol;
        rz = *reinterpret_cast<const hf4*>(xz16 + a1);
        rh = *reinterpret_cast<const f32x4*>(out + a1);
    }
    __syncthreads();

    for (int j = 0; j < NBLK; ++j) {
        const int jb = j & 1;
#pragma unroll
        for (int s = 0; s < 8; ++s) {
            // staged x reads (broadcast per og-pair)
            const float xzc = (float)xzs[jb][s][og];
            const float xhc = xhs[jb][s][og];
            // matvec slice: 128 dot2, 4 chains per matrix; skewed base q*160
            const _Float16* hsl = &hbuf[s & 1][q * 160];
            float z0 = 0.f, z1 = 0.f, z2 = 0.f, z3 = 0.f;
            float h0 = 0.f, h1 = 0.f, h2 = 0.f, h3 = 0.f;
#pragma unroll
            for (int i = 0; i < 16; ++i) {
                const int off = 8 * i + ((i >> 2) << 3);   // skip skew gaps
                const hf8 hv = *reinterpret_cast<const hf8*>(hsl + off);
                const hf2 p0 = __builtin_shufflevector(hv, hv, 0, 1);
                const hf2 p1 = __builtin_shufflevector(hv, hv, 2, 3);
                const hf2 p2 = __builtin_shufflevector(hv, hv, 4, 5);
                const hf2 p3 = __builtin_shufflevector(hv, hv, 6, 7);
                z0 = dot2(p0, uz[4*i+0], z0);
                z1 = dot2(p1, uz[4*i+1], z1);
                z2 = dot2(p2, uz[4*i+2], z2);
                z3 = dot2(p3, uz[4*i+3], z3);
                h0 = dot2(p0, uh[4*i+0], h0);
                h1 = dot2(p1, uh[4*i+1], h1);
                h2 = dot2(p2, uh[4*i+2], h2);
                h3 = dot2(p3, uh[4*i+3], h3);
            }
            float accz = (z0 + z1) + (z2 + z3);
            float acch = (h0 + h1) + (h2 + h3);
            // reduce over the 2 q-lanes: one DPP quad_perm xor1
            accz = dpp_add<0xB1>(accz);
            acch = dpp_add<0xB1>(acch);
            // epilogue: both q-lanes compute (replicated), q==0 stores
            const float z  = fast_sigmoid(accz + xzc);
            const float th = fast_tanh(acch + xhc);
            hp = fmaf(z, th - hp, hp);
            if (q == 0) {
                *pst = hp;                       // fire-and-forget HBM store
                hbuf[(s + 1) & 1][og_sk] = (_Float16)hp;
            }
            pst += (size_t)BATCH * HID;
            // block boundary: relay regs -> LDS, issue loads 2 blocks ahead
            if (s == 7 && j + 1 < NBLK) {
                *reinterpret_cast<hf4*>(&xzs[jb ^ 1][srow][scol])   = rz;
                *reinterpret_cast<f32x4*>(&xhs[jb ^ 1][srow][scol]) = rh;
                int trow = 8 * (j + 2) + srow;
                if (trow >= SEQ) trow = SEQ - 1;     // tail clamp (unused)
                const size_t an = ((size_t)trow * BATCH + b) * HID + scol;
                rz = *reinterpret_cast<const hf4*>(xz16 + an);
                rh = *reinterpret_cast<const f32x4*>(out + an);
            }
            bar_lds();
        }
    }

    if (q == 0) {
        h_final[(size_t)b * HID + og] = hp;
    }
}

extern "C" void kernel_launch(void* const* d_in, const int* in_sizes, int n_in,
                              void* d_out, int out_size, void* d_ws, size_t ws_size,
                              hipStream_t stream) {
    const float* x      = (const float*)d_in[0];
    const float* hidden = (const float*)d_in[1];
    const float* Wz     = (const float*)d_in[2];
    const float* bz     = (const float*)d_in[3];
    const float* Uz     = (const float*)d_in[4];
    const float* cz     = (const float*)d_in[5];
    const float* Wh     = (const float*)d_in[6];
    const float* bh     = (const float*)d_in[7];
    const float* Uh     = (const float*)d_in[8];
    const float* ch     = (const float*)d_in[9];

    float* out     = (float*)d_out;                        // [SEQ*BATCH*HID]
    float* h_final = out + (size_t)SEQ * BATCH * HID;      // [BATCH*HID]

    _Float16* xz16 = (_Float16*)d_ws;                               // 64 MiB
    _Float16* W16  = (_Float16*)((char*)d_ws + ((size_t)64 << 20)); // 256 KiB

    w16_kernel<<<512, 256, 0, stream>>>(Wz, Wh, W16);

    proj_mfma_kernel<<<(SEQ * BATCH) / 16, 256, 0, stream>>>(
        x, W16, bz, cz, bh, ch, xz16, out);

    rec_dot2_kernel<<<BATCH, 512, 0, stream>>>(
        hidden, Uz, Uh, xz16, out, h_final);
}